// Round 1
// baseline (78.409 us; speedup 1.0000x reference)
//
#include <hip/hip_runtime.h>

// PulseLoss fused kernel for MI355X.
// Reference: gaussian-smeared target (sigma=2) -> BCE(mean) + 0.1*mean(|count diff|).
// Key facts exploited:
//  - K(d) = exp(-d^2/8) underflows f32 for |d| > ~30  -> truncate at RADIUS=32.
//  - peaks are sparse (~16 per 8192 row)              -> peak-list gather, not T x T.
//  - log clamp at -100 never fires for pred in [1e-6, 1-1e-6] (kept anyway).
// One block per batch row (32 blocks x 256 threads). Per-row counts are exact
// ints; bce partial + |count diff| accumulate into d_ws via device-scope
// atomics; last finished block (completion counter) writes the 3 outputs.

#define BATCH    32
#define SEQ_T    8192
#define RADIUS   32
#define MAXPEAKS 1024
#define NTHREADS 256

__global__ __launch_bounds__(NTHREADS) void pulse_loss_kernel(
    const float* __restrict__ pred,
    const float* __restrict__ tgt,
    float* __restrict__ out,
    float* __restrict__ ws)
{
    const int b   = blockIdx.x;
    const int tid = threadIdx.x;
    const float* __restrict__ prow = pred + (size_t)b * SEQ_T;
    const float* __restrict__ trow = tgt  + (size_t)b * SEQ_T;

    __shared__ int   s_npeaks;
    __shared__ int   s_peaks[MAXPEAKS];
    __shared__ float s_K[2 * RADIUS + 1];
    __shared__ float s_bce[NTHREADS / 64];
    __shared__ int   s_cnt[NTHREADS / 64];

    if (tid == 0) s_npeaks = 0;
    if (tid <= 2 * RADIUS) {
        float d = (float)(tid - RADIUS);
        s_K[tid] = __expf(-0.125f * d * d);   // exp(-0.5*(d/sigma)^2), sigma=2
    }
    __syncthreads();

    // Phase 1: gather peak positions for this row.
    for (int i = tid; i < SEQ_T; i += NTHREADS) {
        if (trow[i] > 0.0f) {
            int idx = atomicAdd(&s_npeaks, 1);
            if (idx < MAXPEAKS) s_peaks[idx] = i;
        }
    }
    __syncthreads();
    const int np        = min(s_npeaks, MAXPEAKS);
    const int tgt_count = s_npeaks;   // target values are exactly 1.0 at peaks

    // Phase 2: per-element gaussian target + BCE + pred peak count.
    float bce  = 0.0f;
    int   cntp = 0;
    for (int i = tid; i < SEQ_T; i += NTHREADS) {
        float p = prow[i];
        float g = 0.0f;
        for (int k = 0; k < np; ++k) {
            int d = i - s_peaks[k];
            if (d >= -RADIUS && d <= RADIUS) g += s_K[d + RADIUS];
        }
        g = fminf(g, 1.0f);   // clip(0,1); lower bound automatic (all terms >= 0)
        float lp  = fmaxf(logf(p),    -100.0f);
        float l1p = fmaxf(log1pf(-p), -100.0f);
        bce  += g * lp + (1.0f - g) * l1p;
        cntp += (p > 0.5f) ? 1 : 0;
    }

    // Phase 3: block reduction (wave64 shuffle + LDS across 4 waves).
    #pragma unroll
    for (int off = 32; off > 0; off >>= 1) {
        bce  += __shfl_down(bce,  off);
        cntp += __shfl_down(cntp, off);
    }
    const int wid = tid >> 6;
    const int lane = tid & 63;
    if (lane == 0) { s_bce[wid] = bce; s_cnt[wid] = cntp; }
    __syncthreads();

    if (tid == 0) {
        float tb = 0.0f;
        int   tc = 0;
        #pragma unroll
        for (int w = 0; w < NTHREADS / 64; ++w) { tb += s_bce[w]; tc += s_cnt[w]; }

        const float diff = fabsf((float)tc - (float)tgt_count);
        atomicAdd(&ws[0], tb);    // sum of (gt*log p + (1-gt)*log(1-p))
        atomicAdd(&ws[1], diff);  // sum over rows of |count diff|
        __threadfence();          // make partials visible device-wide

        int done = atomicAdd((int*)(ws + 2), 1);
        if (done == BATCH - 1) {
            // last block: coherent read of accumulators via atomic no-op add
            float sb = atomicAdd(&ws[0], 0.0f);
            float sd = atomicAdd(&ws[1], 0.0f);
            float bce_loss   = -sb / (float)(BATCH * SEQ_T);
            float count_loss = 0.1f * sd / (float)BATCH;
            out[0] = bce_loss + count_loss;
            out[1] = bce_loss;
            out[2] = count_loss;
        }
    }
}

extern "C" void kernel_launch(void* const* d_in, const int* in_sizes, int n_in,
                              void* d_out, int out_size, void* d_ws, size_t ws_size,
                              hipStream_t stream) {
    const float* pred = (const float*)d_in[0];
    const float* tgt  = (const float*)d_in[1];
    float*       out  = (float*)d_out;
    float*       ws   = (float*)d_ws;

    // zero the 3 accumulator slots (bce sum, diff sum, completion counter);
    // required every call since ws is not re-poisoned between graph replays.
    hipMemsetAsync(ws, 0, 16, stream);
    pulse_loss_kernel<<<dim3(BATCH), dim3(NTHREADS), 0, stream>>>(pred, tgt, out, ws);
}

// Round 2
// 26.127 us; speedup vs baseline: 3.0011x; 3.0011x over previous
//
#include <hip/hip_runtime.h>

// PulseLoss fused kernel for MI355X — round 2: chunked decomposition.
//
// Math facts exploited:
//  - K(d) = exp(-d^2/8) underflows f32 for |d| >= 29 -> each 1024-elem chunk
//    only needs target peaks in a +-32 halo. No global per-row peak gather.
//  - peaks sparse (~2 per chunk) -> peak-list, not 65-tap convolution.
//  - log clamp at -100 never fires for pred in [1e-6, 1-1e-6] (kept anyway).
//  - log1p(-p) == log(1-p) exactly in f32 (Sterbenz for p>=0.5, <=1ulp else).
//
// Decomposition: 32 rows x 8 chunks = 256 blocks x 256 threads; each thread
// owns one float4 of pred. Per-row signed count diff (pred>0.5 minus target
// peaks) accumulates via device atomics into d_ws; BCE partial sums into a
// float accumulator. Last block (completion counter) does |.| per row and
// writes the 3 outputs.

#define BATCH    32
#define SEQ_T    8192
#define CHUNK    1024
#define NCHUNKS  (SEQ_T / CHUNK)
#define NBLOCKS  (BATCH * NCHUNKS)
#define HALO     32
#define MAXPEAKS 64
#define NTHREADS 256

__global__ __launch_bounds__(NTHREADS) void pulse_loss_kernel(
    const float* __restrict__ pred,
    const float* __restrict__ tgt,
    float* __restrict__ out,
    float* __restrict__ ws)   // ws[0]=bce sum (f32), ws[1]=ctr (int), ws[2..33]=per-row dcnt (int)
{
    const int tid = threadIdx.x;
    const int blk = blockIdx.x;
    const int b   = blk >> 3;            // row
    const int c0  = (blk & 7) * CHUNK;   // chunk start within row
    const float* __restrict__ prow = pred + (size_t)b * SEQ_T;
    const float* __restrict__ trow = tgt  + (size_t)b * SEQ_T;

    __shared__ int   s_npeaks;
    __shared__ int   s_peaks[MAXPEAKS];  // global (row) positions
    __shared__ float s_K[2 * HALO + 1];
    __shared__ float s_bce[NTHREADS / 64];
    __shared__ int   s_cnt[NTHREADS / 64];

    if (tid == 0) s_npeaks = 0;
    if (tid <= 2 * HALO) {
        float d = (float)(tid - HALO);
        s_K[tid] = __expf(-0.125f * d * d);   // exp(-0.5*(d/sigma)^2), sigma=2
    }
    __syncthreads();

    // Phase 1: scan target over [c0-HALO, c0+CHUNK+HALO) for peaks;
    // count interior peaks (each interior position visited exactly once).
    int cnt_t = 0;
    for (int i = tid; i < CHUNK + 2 * HALO; i += NTHREADS) {
        int gi = c0 - HALO + i;
        if (gi >= 0 && gi < SEQ_T) {
            if (trow[gi] > 0.0f) {
                int idx = atomicAdd(&s_npeaks, 1);
                if (idx < MAXPEAKS) s_peaks[idx] = gi;
                if (gi >= c0 && gi < c0 + CHUNK) cnt_t++;
            }
        }
    }
    __syncthreads();
    const int np = min(s_npeaks, MAXPEAKS);

    // Phase 2: one float4 of pred per thread.
    const float4 p4 = ((const float4*)(prow + c0))[tid];
    float bce  = 0.0f;
    int   dcnt = -cnt_t;
    #pragma unroll
    for (int j = 0; j < 4; ++j) {
        const float p = (j == 0) ? p4.x : (j == 1) ? p4.y : (j == 2) ? p4.z : p4.w;
        const int   i = c0 + tid * 4 + j;
        float g = 0.0f;
        for (int k = 0; k < np; ++k) {
            int d = i - s_peaks[k];
            if (d >= -HALO && d <= HALO) g += s_K[d + HALO];
        }
        g = fminf(g, 1.0f);
        float lp  = fmaxf(__logf(p),        -100.0f);
        float l1p = fmaxf(__logf(1.0f - p), -100.0f);
        bce  += l1p + g * (lp - l1p);
        dcnt += (p > 0.5f) ? 1 : 0;
    }

    // Phase 3: block reduction (wave64 shuffle + LDS across 4 waves).
    #pragma unroll
    for (int off = 32; off > 0; off >>= 1) {
        bce  += __shfl_down(bce,  off);
        dcnt += __shfl_down(dcnt, off);
    }
    const int wid  = tid >> 6;
    const int lane = tid & 63;
    if (lane == 0) { s_bce[wid] = bce; s_cnt[wid] = dcnt; }
    __syncthreads();

    if (tid == 0) {
        float tb = 0.0f;
        int   tc = 0;
        #pragma unroll
        for (int w = 0; w < NTHREADS / 64; ++w) { tb += s_bce[w]; tc += s_cnt[w]; }

        int* wsI = (int*)ws;
        atomicAdd(&ws[0], tb);           // BCE partial (device scope)
        atomicAdd(&wsI[2 + b], tc);      // per-row signed count diff
        __threadfence();

        int done = atomicAdd(&wsI[1], 1);
        if (done == NBLOCKS - 1) {
            float sb = atomicAdd(&ws[0], 0.0f);   // coherent read
            float sd = 0.0f;
            for (int r = 0; r < BATCH; ++r) {
                int dc = atomicAdd(&wsI[2 + r], 0);
                sd += fabsf((float)dc);
            }
            float bce_loss   = -sb / (float)(BATCH * SEQ_T);
            float count_loss = 0.1f * sd / (float)BATCH;
            out[0] = bce_loss + count_loss;
            out[1] = bce_loss;
            out[2] = count_loss;
        }
    }
}

extern "C" void kernel_launch(void* const* d_in, const int* in_sizes, int n_in,
                              void* d_out, int out_size, void* d_ws, size_t ws_size,
                              hipStream_t stream) {
    const float* pred = (const float*)d_in[0];
    const float* tgt  = (const float*)d_in[1];
    float*       out  = (float*)d_out;
    float*       ws   = (float*)d_ws;

    // zero accumulators: ws[0] bce, ws[1] ctr, ws[2..33] per-row dcnt
    hipMemsetAsync(ws, 0, 34 * sizeof(float), stream);
    pulse_loss_kernel<<<dim3(NBLOCKS), dim3(NTHREADS), 0, stream>>>(pred, tgt, out, ws);
}

// Round 3
// 11.611 us; speedup vs baseline: 6.7527x; 2.2501x over previous
//
#include <hip/hip_runtime.h>

// PulseLoss fused kernels for MI355X — round 3: no atomics, no memset.
//
// Math facts exploited:
//  - K(d) = exp(-d^2/8) underflows f32 for |d| >= 29 -> each 1024-elem chunk
//    only needs target peaks in a +-32 halo; peaks sparse (~2/chunk).
//  - __expf(-0.125*33^2) underflows to exactly 0 -> clamped table lookup
//    replaces the branch in the gaussian inner loop.
//  - log clamp at -100 never fires for pred in [1e-6, 1-1e-6] (kept anyway).
//  - log1p(-p) == log(1-p) exactly in f32 (Sterbenz for p>=0.5).
//
// Structure (round-2 post-mortem): device atomics to shared cachelines +
// completion counter + memset node dominated the graph. Now: 256 blocks each
// plain-store {bce partial, signed count diff} to UNIQUE ws slots (all slots
// rewritten every call -> deterministic, no pre-zeroing), then a 1-block
// finalize kernel reduces 512 words and writes the 3 outputs. Zero atomics
// on the global path, zero fill nodes.

#define BATCH    32
#define SEQ_T    8192
#define CHUNK    1024
#define NCHUNKS  (SEQ_T / CHUNK)
#define NBLOCKS  (BATCH * NCHUNKS)   // 256
#define HALO     32
#define KTAB     67                  // d in [-33, 33]; edges underflow to 0
#define MAXPEAKS 64
#define NTHREADS 256

__global__ __launch_bounds__(NTHREADS) void pulse_loss_main(
    const float* __restrict__ pred,
    const float* __restrict__ tgt,
    float* __restrict__ ws)   // ws[0..255]=bce partials (f32), ws[256..511]=dcnt (int)
{
    const int tid = threadIdx.x;
    const int blk = blockIdx.x;
    const int b   = blk >> 3;            // row
    const int c0  = (blk & 7) * CHUNK;   // chunk start within row
    const float* __restrict__ prow = pred + (size_t)b * SEQ_T;
    const float* __restrict__ trow = tgt  + (size_t)b * SEQ_T;

    __shared__ int   s_npeaks;
    __shared__ int   s_peaks[MAXPEAKS];  // row-global positions
    __shared__ float s_K[KTAB];
    __shared__ float s_bce[NTHREADS / 64];
    __shared__ int   s_cnt[NTHREADS / 64];

    if (tid == 0) s_npeaks = 0;
    if (tid < KTAB) {
        float d = (float)(tid - 33);
        s_K[tid] = __expf(-0.125f * d * d);  // exp(-0.5*(d/2)^2); 0 at edges
    }
    __syncthreads();

    // Phase 1: scan target over [c0-HALO, c0+CHUNK+HALO); count interior peaks.
    int cnt_t = 0;
    for (int i = tid; i < CHUNK + 2 * HALO; i += NTHREADS) {
        int gi = c0 - HALO + i;
        if (gi >= 0 && gi < SEQ_T) {
            if (trow[gi] > 0.0f) {
                int idx = atomicAdd(&s_npeaks, 1);   // LDS atomic, ~2 hits/block
                if (idx < MAXPEAKS) s_peaks[idx] = gi;
                if (gi >= c0 && gi < c0 + CHUNK) cnt_t++;
            }
        }
    }
    __syncthreads();
    const int np = min(s_npeaks, MAXPEAKS);

    // Phase 2: one float4 of pred per thread; branch-free gaussian gather.
    const float4 p4 = ((const float4*)(prow + c0))[tid];
    float bce  = 0.0f;
    int   dcnt = -cnt_t;
    #pragma unroll
    for (int j = 0; j < 4; ++j) {
        const float p = (j == 0) ? p4.x : (j == 1) ? p4.y : (j == 2) ? p4.z : p4.w;
        const int   i = c0 + tid * 4 + j;
        float g = 0.0f;
        for (int k = 0; k < np; ++k) {
            int d = i - s_peaks[k];
            d = min(max(d, -33), 33);
            g += s_K[d + 33];            // 0 outside the true support
        }
        g = fminf(g, 1.0f);
        float lp  = fmaxf(__logf(p),        -100.0f);
        float l1p = fmaxf(__logf(1.0f - p), -100.0f);
        bce  += l1p + g * (lp - l1p);
        dcnt += (p > 0.5f) ? 1 : 0;
    }

    // Phase 3: block reduction (wave64 shuffle + LDS across 4 waves).
    #pragma unroll
    for (int off = 32; off > 0; off >>= 1) {
        bce  += __shfl_down(bce,  off);
        dcnt += __shfl_down(dcnt, off);
    }
    const int wid  = tid >> 6;
    const int lane = tid & 63;
    if (lane == 0) { s_bce[wid] = bce; s_cnt[wid] = dcnt; }
    __syncthreads();

    if (tid == 0) {
        float tb = 0.0f;
        int   tc = 0;
        #pragma unroll
        for (int w = 0; w < NTHREADS / 64; ++w) { tb += s_bce[w]; tc += s_cnt[w]; }
        ws[blk] = tb;                         // unique slot: plain store
        ((int*)ws)[NBLOCKS + blk] = tc;       // unique slot: plain store
    }
}

__global__ __launch_bounds__(NBLOCKS) void pulse_loss_finalize(
    const float* __restrict__ ws,
    float* __restrict__ out)
{
    const int t = threadIdx.x;               // 256 threads == NBLOCKS
    float bce = ws[t];
    int   dc  = ((const int*)ws)[NBLOCKS + t];

    // dcnt: 8 consecutive slots per row -> segmented 8-wide sum, then |.|
    dc += __shfl_down(dc, 4, 8);
    dc += __shfl_down(dc, 2, 8);
    dc += __shfl_down(dc, 1, 8);
    float ad = ((t & 7) == 0) ? fabsf((float)dc) : 0.0f;

    #pragma unroll
    for (int off = 32; off > 0; off >>= 1) {
        bce += __shfl_down(bce, off);
        ad  += __shfl_down(ad,  off);
    }

    __shared__ float s_b[4], s_a[4];
    const int wid  = t >> 6;
    const int lane = t & 63;
    if (lane == 0) { s_b[wid] = bce; s_a[wid] = ad; }
    __syncthreads();

    if (t == 0) {
        float sb = 0.0f, sd = 0.0f;
        #pragma unroll
        for (int w = 0; w < 4; ++w) { sb += s_b[w]; sd += s_a[w]; }
        float bce_loss   = -sb / (float)(BATCH * SEQ_T);
        float count_loss = 0.1f * sd / (float)BATCH;
        out[0] = bce_loss + count_loss;
        out[1] = bce_loss;
        out[2] = count_loss;
    }
}

extern "C" void kernel_launch(void* const* d_in, const int* in_sizes, int n_in,
                              void* d_out, int out_size, void* d_ws, size_t ws_size,
                              hipStream_t stream) {
    const float* pred = (const float*)d_in[0];
    const float* tgt  = (const float*)d_in[1];
    float*       out  = (float*)d_out;
    float*       ws   = (float*)d_ws;

    pulse_loss_main<<<dim3(NBLOCKS), dim3(NTHREADS), 0, stream>>>(pred, tgt, ws);
    pulse_loss_finalize<<<dim3(1), dim3(NBLOCKS), 0, stream>>>(ws, out);
}